// Round 5
// baseline (1147.119 us; speedup 1.0000x reference)
//
#include <hip/hip_runtime.h>

#define NV 50000
#define NE 800000
#define CVT_N (NV * 128 / 4)   // 1,600,000
#define PW_N  114688

typedef __bf16 bf16x8 __attribute__((ext_vector_type(8)));
typedef __bf16 bf16x4 __attribute__((ext_vector_type(4)));
typedef float  f32x4  __attribute__((ext_vector_type(4)));

static __device__ __forceinline__ f32x4 mfma16(bf16x8 a, bf16x8 b, f32x4 c) {
  return __builtin_amdgcn_mfma_f32_16x16x32_bf16(a, b, c, 0, 0, 0);
}

// ---- fused prep: h->bf16, 5 weight transposes, dst histogram ----
__global__ void prep_kernel(const float* __restrict__ h, __bf16* __restrict__ hb,
    const float* __restrict__ W1, const float* __restrict__ W2, const float* __restrict__ W3,
    const float* __restrict__ Wn1, const float* __restrict__ Wn2,
    __bf16* __restrict__ w1t, __bf16* __restrict__ w2t, __bf16* __restrict__ w3t,
    __bf16* __restrict__ wn1t, __bf16* __restrict__ wn2t,
    const int* __restrict__ ei, int* __restrict__ counts)
{
  int i = blockIdx.x * blockDim.x + threadIdx.x;
  if (i < CVT_N) {
    f32x4 v = reinterpret_cast<const f32x4*>(h)[i];
    bf16x4 o;
    o[0] = (__bf16)v[0]; o[1] = (__bf16)v[1]; o[2] = (__bf16)v[2]; o[3] = (__bf16)v[3];
    reinterpret_cast<bf16x4*>(hb)[i] = o;
    return;
  }
  i -= CVT_N;
  if (i < PW_N) {
    const float* w; __bf16* wt; int K;
    if      (i < 32768)              { w = W1;  wt = w1t;  K = 256; }
    else if (i < 49152) { i -= 32768; w = W2;  wt = w2t;  K = 128; }
    else if (i < 65536) { i -= 49152; w = W3;  wt = w3t;  K = 128; }
    else if (i < 98304) { i -= 65536; w = Wn1; wt = wn1t; K = 256; }
    else                { i -= 98304; w = Wn2; wt = wn2t; K = 128; }
    int n = i / K, k = i % K;
    wt[i] = (__bf16)w[k * 128 + n];
    return;
  }
  i -= PW_N;
  if (i < NE) atomicAdd(&counts[ei[NE + i]], 1);
}

__global__ __launch_bounds__(1024)
void scan_kernel(const int* __restrict__ counts, int* __restrict__ offsets,
                 int* __restrict__ cursor) {
  __shared__ int part[1024];
  const int t = threadIdx.x;
  const int C = (NV + 1023) / 1024;
  const int base = t * C;
  int s = 0;
  for (int i = 0; i < C; i++) {
    int idx = base + i;
    if (idx < NV) s += counts[idx];
  }
  part[t] = s;
  __syncthreads();
  for (int off = 1; off < 1024; off <<= 1) {
    int v = 0;
    if (t >= off) v = part[t - off];
    __syncthreads();
    if (t >= off) part[t] += v;
    __syncthreads();
  }
  int run = (t == 0) ? 0 : part[t - 1];
  for (int i = 0; i < C; i++) {
    int idx = base + i;
    if (idx < NV) {
      offsets[idx] = run;
      cursor[idx] = run;
      run += counts[idx];
    }
  }
  if (t == 1023) offsets[NV] = run;
}

__global__ void permute_kernel(const int* __restrict__ ei, int* __restrict__ cursor,
                               int2* __restrict__ pairs) {
  int e = blockIdx.x * blockDim.x + threadIdx.x;
  if (e < NE) {
    int s = ei[e], d = ei[NE + e];
    int pos = atomicAdd(&cursor[d], 1);
    pairs[pos] = make_int2(s, d);
  }
}

// ================= edge kernel: 1 barrier, wave-private layers =================
// Block: 256 thr / 4 waves / 64 edges. Phase 1: cooperative swizzled gather of
// X[64][256] ([h_src | h_dst]). After ONE barrier, wave w owns rows w*16..w*16+15:
// it computes ALL 128 out-features for its 16 edges (acc = 8 x f32x4 = 32 VGPR),
// relu buffers round-trip through its own rows only -> no more __syncthreads.
// LDS swizzle: 16B chunk c8 stored at (c8 ^ (row & 7)) -> <=2-way conflicts (free).
__global__ __launch_bounds__(256, 4)
void edge_kernel(const __bf16* __restrict__ hb, const int2* __restrict__ pairs,
                 const __bf16* __restrict__ w1t, const float* __restrict__ b1,
                 const __bf16* __restrict__ w2t, const float* __restrict__ b2,
                 const __bf16* __restrict__ w3t, const float* __restrict__ b3,
                 __bf16* __restrict__ msg)
{
  __shared__ __align__(16) __bf16 X[64 * 256];
  const int t = threadIdx.x;
  const int lane = t & 63;
  const int wave = t >> 6;
  const int quad = lane >> 4;
  const int l15  = lane & 15;
  const int ebase = blockIdx.x * 64;

  // ---- phase 1: gather (64 rows x 32 chunks of 16B) ----
#pragma unroll
  for (int it = 0; it < 8; it++) {
    int g = it * 256 + t;
    int row = g >> 5, c8 = g & 31;
    int2 pr = pairs[ebase + row];
    int node = (c8 < 16) ? pr.x : pr.y;
    bf16x8 v = *reinterpret_cast<const bf16x8*>(hb + (long long)node * 128 + (c8 & 15) * 8);
    *reinterpret_cast<bf16x8*>(&X[row * 256 + ((c8 ^ (row & 7)) * 8)]) = v;
  }
  __syncthreads();   // the only barrier

  const int myrow = wave * 16 + l15;
  __bf16* Xr = &X[myrow * 256];
  const int sw = myrow & 7;

  f32x4 acc[8];
#pragma unroll
  for (int mt = 0; mt < 8; mt++) acc[mt] = (f32x4){0.f, 0.f, 0.f, 0.f};

  // ---- layer 1: K=256 ----
#pragma unroll
  for (int s = 0; s < 8; s++) {
    bf16x8 B = *reinterpret_cast<const bf16x8*>(&Xr[((s * 4 + quad) ^ sw) * 8]);
    const int k = s * 32 + quad * 8;
#pragma unroll
    for (int mt = 0; mt < 8; mt++) {
      bf16x8 A = *reinterpret_cast<const bf16x8*>(w1t + (mt * 16 + l15) * 256 + k);
      acc[mt] = mfma16(A, B, acc[mt]);
    }
  }
  // epi1: +b1, relu -> own row cols 0..127 (8B swizzled writes)
#pragma unroll
  for (int mt = 0; mt < 8; mt++) {
    f32x4 bias = *reinterpret_cast<const f32x4*>(b1 + mt * 16 + quad * 4);
    bf16x4 o;
#pragma unroll
    for (int r = 0; r < 4; r++) { float x = acc[mt][r] + bias[r]; o[r] = (__bf16)(x > 0.f ? x : 0.f); }
    *reinterpret_cast<bf16x4*>(&Xr[(((mt * 2 + (quad >> 1)) ^ sw) * 8) + (quad & 1) * 4]) = o;
    acc[mt] = (f32x4){0.f, 0.f, 0.f, 0.f};
  }

  // ---- layer 2: K=128 ----
#pragma unroll
  for (int s = 0; s < 4; s++) {
    bf16x8 B = *reinterpret_cast<const bf16x8*>(&Xr[((s * 4 + quad) ^ sw) * 8]);
    const int k = s * 32 + quad * 8;
#pragma unroll
    for (int mt = 0; mt < 8; mt++) {
      bf16x8 A = *reinterpret_cast<const bf16x8*>(w2t + (mt * 16 + l15) * 128 + k);
      acc[mt] = mfma16(A, B, acc[mt]);
    }
  }
#pragma unroll
  for (int mt = 0; mt < 8; mt++) {
    f32x4 bias = *reinterpret_cast<const f32x4*>(b2 + mt * 16 + quad * 4);
    bf16x4 o;
#pragma unroll
    for (int r = 0; r < 4; r++) { float x = acc[mt][r] + bias[r]; o[r] = (__bf16)(x > 0.f ? x : 0.f); }
    *reinterpret_cast<bf16x4*>(&Xr[(((mt * 2 + (quad >> 1)) ^ sw) * 8) + (quad & 1) * 4]) = o;
    acc[mt] = (f32x4){0.f, 0.f, 0.f, 0.f};
  }

  // ---- layer 3: K=128 ----
#pragma unroll
  for (int s = 0; s < 4; s++) {
    bf16x8 B = *reinterpret_cast<const bf16x8*>(&Xr[((s * 4 + quad) ^ sw) * 8]);
    const int k = s * 32 + quad * 8;
#pragma unroll
    for (int mt = 0; mt < 8; mt++) {
      bf16x8 A = *reinterpret_cast<const bf16x8*>(w3t + (mt * 16 + l15) * 128 + k);
      acc[mt] = mfma16(A, B, acc[mt]);
    }
  }
  // epi3: +b3 (no relu) -> own row
#pragma unroll
  for (int mt = 0; mt < 8; mt++) {
    f32x4 bias = *reinterpret_cast<const f32x4*>(b3 + mt * 16 + quad * 4);
    bf16x4 o;
#pragma unroll
    for (int r = 0; r < 4; r++) o[r] = (__bf16)(acc[mt][r] + bias[r]);
    *reinterpret_cast<bf16x4*>(&Xr[(((mt * 2 + (quad >> 1)) ^ sw) * 8) + (quad & 1) * 4]) = o;
  }

  // ---- phase 3: wave stores its own 16 rows, coalesced (16 rows x 16 chunks) ----
#pragma unroll
  for (int it = 0; it < 4; it++) {
    int g = it * 64 + lane;
    int r16 = g >> 4, c8 = g & 15;
    int row = wave * 16 + r16;
    bf16x8 v = *reinterpret_cast<const bf16x8*>(&X[row * 256 + ((c8 ^ (row & 7)) * 8)]);
    *reinterpret_cast<bf16x8*>(msg + (long long)(ebase + row) * 128 + c8 * 8) = v;
  }
}

// ================= streaming aggregation: one wave per node =================
// Sorted msg rows are contiguous per node: 64 lanes read 4 rows/iter (1 KB
// coalesced bursts), fp32 accumulate, shfl-xor combine, bf16 store.
__global__ __launch_bounds__(256)
void agg_kernel(const __bf16* __restrict__ msg, const int* __restrict__ offsets,
                __bf16* __restrict__ aggb)
{
  const int lane = threadIdx.x & 63;
  const int wave = threadIdx.x >> 6;
  const int n = blockIdx.x * 4 + wave;
  if (n >= NV) return;
  const int grp = lane >> 4, c8 = lane & 15;
  const int start = offsets[n], end = offsets[n + 1];
  float a[8];
#pragma unroll
  for (int j = 0; j < 8; j++) a[j] = 0.f;
  for (int r = start + grp; r < end; r += 4) {
    bf16x8 v = *reinterpret_cast<const bf16x8*>(msg + (long long)r * 128 + c8 * 8);
#pragma unroll
    for (int j = 0; j < 8; j++) a[j] += (float)v[j];
  }
#pragma unroll
  for (int j = 0; j < 8; j++) {
    a[j] += __shfl_xor(a[j], 16);
    a[j] += __shfl_xor(a[j], 32);
  }
  if (grp == 0) {
    bf16x8 o;
#pragma unroll
    for (int j = 0; j < 8; j++) o[j] = (__bf16)a[j];
    *reinterpret_cast<bf16x8*>(aggb + (long long)n * 128 + c8 * 8) = o;
  }
}

// ---- shared node-MLP tail (X[64][256] = [h | agg], swizzled) ----
static __device__ __forceinline__ void node_mlp_tail(
    __bf16* X, int t, int nbase,
    const __bf16* __restrict__ wn1t, const float* __restrict__ bn1,
    const __bf16* __restrict__ wn2t, const float* __restrict__ bn2,
    float* __restrict__ out)
{
  const int lane = t & 63;
  const int wave = t >> 6;
  const int quad = lane >> 4;
  const int l15  = lane & 15;
  const int myrow = wave * 16 + l15;
  __bf16* Xr = &X[myrow * 256];
  const int sw = myrow & 7;

  f32x4 acc[8];
#pragma unroll
  for (int mt = 0; mt < 8; mt++) acc[mt] = (f32x4){0.f, 0.f, 0.f, 0.f};

#pragma unroll
  for (int s = 0; s < 8; s++) {
    bf16x8 B = *reinterpret_cast<const bf16x8*>(&Xr[((s * 4 + quad) ^ sw) * 8]);
    const int k = s * 32 + quad * 8;
#pragma unroll
    for (int mt = 0; mt < 8; mt++) {
      bf16x8 A = *reinterpret_cast<const bf16x8*>(wn1t + (mt * 16 + l15) * 256 + k);
      acc[mt] = mfma16(A, B, acc[mt]);
    }
  }
#pragma unroll
  for (int mt = 0; mt < 8; mt++) {
    f32x4 bias = *reinterpret_cast<const f32x4*>(bn1 + mt * 16 + quad * 4);
    bf16x4 o;
#pragma unroll
    for (int r = 0; r < 4; r++) { float x = acc[mt][r] + bias[r]; o[r] = (__bf16)(x > 0.f ? x : 0.f); }
    *reinterpret_cast<bf16x4*>(&Xr[(((mt * 2 + (quad >> 1)) ^ sw) * 8) + (quad & 1) * 4]) = o;
    acc[mt] = (f32x4){0.f, 0.f, 0.f, 0.f};
  }
#pragma unroll
  for (int s = 0; s < 4; s++) {
    bf16x8 B = *reinterpret_cast<const bf16x8*>(&Xr[((s * 4 + quad) ^ sw) * 8]);
    const int k = s * 32 + quad * 8;
#pragma unroll
    for (int mt = 0; mt < 8; mt++) {
      bf16x8 A = *reinterpret_cast<const bf16x8*>(wn2t + (mt * 16 + l15) * 128 + k);
      acc[mt] = mfma16(A, B, acc[mt]);
    }
  }
  const int n = nbase + myrow;
  if (n < NV) {
    // lanes (l15, quad 0..3) cover a full 64B line per (l15, mt) -> clean writes
#pragma unroll
    for (int mt = 0; mt < 8; mt++) {
      f32x4 bias = *reinterpret_cast<const f32x4*>(bn2 + mt * 16 + quad * 4);
      f32x4 v;
#pragma unroll
      for (int r = 0; r < 4; r++) v[r] = acc[mt][r] + bias[r];
      *reinterpret_cast<f32x4*>(out + (long long)n * 128 + mt * 16 + quad * 4) = v;
    }
  }
}

// tier A: agg precomputed in aggb -> fully coalesced gather
__global__ __launch_bounds__(256, 4)
void node_kernel_a(const __bf16* __restrict__ hb, const __bf16* __restrict__ aggb,
                   const __bf16* __restrict__ wn1t, const float* __restrict__ bn1,
                   const __bf16* __restrict__ wn2t, const float* __restrict__ bn2,
                   float* __restrict__ out)
{
  __shared__ __align__(16) __bf16 X[64 * 256];
  const int t = threadIdx.x;
  const int nbase = blockIdx.x * 64;
#pragma unroll
  for (int it = 0; it < 8; it++) {
    int g = it * 256 + t;
    int row = g >> 5, c8 = g & 31;
    int n = nbase + row;
    int node = n < NV ? n : NV - 1;
    const __bf16* src = ((c8 < 16) ? hb : aggb) + (long long)node * 128 + (c8 & 15) * 8;
    bf16x8 v = *reinterpret_cast<const bf16x8*>(src);
    *reinterpret_cast<bf16x8*>(&X[row * 256 + ((c8 ^ (row & 7)) * 8)]) = v;
  }
  __syncthreads();
  node_mlp_tail(X, t, nbase, wn1t, bn1, wn2t, bn2, out);
}

// tier B fallback (no aggb workspace): divergent in-kernel aggregation
__global__ __launch_bounds__(256, 4)
void node_kernel_b(const __bf16* __restrict__ hb, const __bf16* __restrict__ msg,
                   const int* __restrict__ offsets,
                   const __bf16* __restrict__ wn1t, const float* __restrict__ bn1,
                   const __bf16* __restrict__ wn2t, const float* __restrict__ bn2,
                   float* __restrict__ out)
{
  __shared__ __align__(16) __bf16 X[64 * 256];
  const int t = threadIdx.x;
  const int nbase = blockIdx.x * 64;
#pragma unroll
  for (int it = 0; it < 4; it++) {
    int g = it * 256 + t;
    int row = g >> 4, c8 = g & 15;
    int n = nbase + row;
    int node = n < NV ? n : NV - 1;
    bf16x8 v = *reinterpret_cast<const bf16x8*>(hb + (long long)node * 128 + c8 * 8);
    *reinterpret_cast<bf16x8*>(&X[row * 256 + ((c8 ^ (row & 7)) * 8)]) = v;
  }
  {
    const int nl = t >> 2, q4 = t & 3;
    const int n = nbase + nl;
    int start = 0, end = 0;
    if (n < NV) { start = offsets[n]; end = offsets[n + 1]; }
    float accv[32];
#pragma unroll
    for (int j = 0; j < 32; j++) accv[j] = 0.f;
    for (int r = start; r < end; r++) {
      const __bf16* row = msg + (long long)r * 128 + q4 * 32;
#pragma unroll
      for (int c = 0; c < 4; c++) {
        bf16x8 v = *reinterpret_cast<const bf16x8*>(row + c * 8);
#pragma unroll
        for (int j = 0; j < 8; j++) accv[c * 8 + j] += (float)v[j];
      }
    }
#pragma unroll
    for (int c = 0; c < 4; c++) {
      int c8 = 16 + q4 * 4 + c;
      bf16x8 o;
#pragma unroll
      for (int j = 0; j < 8; j++) o[j] = (__bf16)accv[c * 8 + j];
      *reinterpret_cast<bf16x8*>(&X[nl * 256 + ((c8 ^ (nl & 7)) * 8)]) = o;
    }
  }
  __syncthreads();
  node_mlp_tail(X, t, nbase, wn1t, bn1, wn2t, bn2, out);
}

static inline size_t align16(size_t x) { return (x + 15) & ~(size_t)15; }

extern "C" void kernel_launch(void* const* d_in, const int* in_sizes, int n_in,
                              void* d_out, int out_size, void* d_ws, size_t ws_size,
                              hipStream_t stream)
{
  const float* h   = (const float*)d_in[0];
  const int*   ei  = (const int*)d_in[1];
  const float* W1  = (const float*)d_in[2];
  const float* b1  = (const float*)d_in[3];
  const float* W2  = (const float*)d_in[4];
  const float* b2  = (const float*)d_in[5];
  const float* W3  = (const float*)d_in[6];
  const float* b3  = (const float*)d_in[7];
  const float* Wn1 = (const float*)d_in[8];
  const float* bn1 = (const float*)d_in[9];
  const float* Wn2 = (const float*)d_in[10];
  const float* bn2 = (const float*)d_in[11];
  float* out = (float*)d_out;

  char* p = (char*)d_ws;
  __bf16* hb   = (__bf16*)p; p += align16((size_t)NV * 128 * 2);
  __bf16* w1t  = (__bf16*)p; p += align16(128 * 256 * 2);
  __bf16* w2t  = (__bf16*)p; p += align16(128 * 128 * 2);
  __bf16* w3t  = (__bf16*)p; p += align16(128 * 128 * 2);
  __bf16* wn1t = (__bf16*)p; p += align16(128 * 256 * 2);
  __bf16* wn2t = (__bf16*)p; p += align16(128 * 128 * 2);
  int* counts  = (int*)p; p += align16((size_t)NV * 4);
  int* offsets = (int*)p; p += align16((size_t)(NV + 1) * 4);
  int* cursor  = (int*)p; p += align16((size_t)NV * 4);
  int2* pairs  = (int2*)p; p += align16((size_t)NE * 8);
  __bf16* msg  = (__bf16*)p; p += align16((size_t)NE * 128 * 2);
  size_t needB = (size_t)(p - (char*)d_ws);
  __bf16* aggb = (__bf16*)p; p += align16((size_t)NV * 128 * 2);
  size_t needA = (size_t)(p - (char*)d_ws);

  hipMemsetAsync(counts, 0, (size_t)NV * 4, stream);
  {
    int total = CVT_N + PW_N + NE;
    prep_kernel<<<(total + 255) / 256, 256, 0, stream>>>(
        h, hb, W1, W2, W3, Wn1, Wn2, w1t, w2t, w3t, wn1t, wn2t, ei, counts);
  }
  scan_kernel<<<1, 1024, 0, stream>>>(counts, offsets, cursor);
  permute_kernel<<<(NE + 255) / 256, 256, 0, stream>>>(ei, cursor, pairs);
  edge_kernel<<<NE / 64, 256, 0, stream>>>(hb, pairs, w1t, b1, w2t, b2, w3t, b3, msg);

  if (ws_size >= needA) {
    agg_kernel<<<(NV + 3) / 4, 256, 0, stream>>>(msg, offsets, aggb);
    node_kernel_a<<<(NV + 63) / 64, 256, 0, stream>>>(hb, aggb, wn1t, bn1, wn2t, bn2, out);
  } else if (ws_size >= needB) {
    node_kernel_b<<<(NV + 63) / 64, 256, 0, stream>>>(hb, msg, offsets, wn1t, bn1, wn2t, bn2, out);
  }
}

// Round 6
// 708.529 us; speedup vs baseline: 1.6190x; 1.6190x over previous
//
#include <hip/hip_runtime.h>

#define NV 50000
#define NE 800000
#define CVT_N (NV * 128 / 4)   // 1,600,000
#define PW_N  114688

typedef __bf16 bf16x8 __attribute__((ext_vector_type(8)));
typedef __bf16 bf16x4 __attribute__((ext_vector_type(4)));
typedef float  f32x4  __attribute__((ext_vector_type(4)));

static __device__ __forceinline__ f32x4 mfma16(bf16x8 a, bf16x8 b, f32x4 c) {
  return __builtin_amdgcn_mfma_f32_16x16x32_bf16(a, b, c, 0, 0, 0);
}

// ---- fused prep: h->bf16, 5 weight transposes, dst histogram ----
__global__ void prep_kernel(const float* __restrict__ h, __bf16* __restrict__ hb,
    const float* __restrict__ W1, const float* __restrict__ W2, const float* __restrict__ W3,
    const float* __restrict__ Wn1, const float* __restrict__ Wn2,
    __bf16* __restrict__ w1t, __bf16* __restrict__ w2t, __bf16* __restrict__ w3t,
    __bf16* __restrict__ wn1t, __bf16* __restrict__ wn2t,
    const int* __restrict__ ei, int* __restrict__ counts)
{
  int i = blockIdx.x * blockDim.x + threadIdx.x;
  if (i < CVT_N) {
    f32x4 v = reinterpret_cast<const f32x4*>(h)[i];
    bf16x4 o;
    o[0] = (__bf16)v[0]; o[1] = (__bf16)v[1]; o[2] = (__bf16)v[2]; o[3] = (__bf16)v[3];
    reinterpret_cast<bf16x4*>(hb)[i] = o;
    return;
  }
  i -= CVT_N;
  if (i < PW_N) {
    const float* w; __bf16* wt; int K;
    if      (i < 32768)              { w = W1;  wt = w1t;  K = 256; }
    else if (i < 49152) { i -= 32768; w = W2;  wt = w2t;  K = 128; }
    else if (i < 65536) { i -= 49152; w = W3;  wt = w3t;  K = 128; }
    else if (i < 98304) { i -= 65536; w = Wn1; wt = wn1t; K = 256; }
    else                { i -= 98304; w = Wn2; wt = wn2t; K = 128; }
    int n = i / K, k = i % K;
    wt[i] = (__bf16)w[k * 128 + n];
    return;
  }
  i -= PW_N;
  if (i < NE) atomicAdd(&counts[ei[NE + i]], 1);
}

__global__ __launch_bounds__(1024)
void scan_kernel(const int* __restrict__ counts, int* __restrict__ offsets,
                 int* __restrict__ cursor) {
  __shared__ int part[1024];
  const int t = threadIdx.x;
  const int C = (NV + 1023) / 1024;
  const int base = t * C;
  int s = 0;
  for (int i = 0; i < C; i++) {
    int idx = base + i;
    if (idx < NV) s += counts[idx];
  }
  part[t] = s;
  __syncthreads();
  for (int off = 1; off < 1024; off <<= 1) {
    int v = 0;
    if (t >= off) v = part[t - off];
    __syncthreads();
    if (t >= off) part[t] += v;
    __syncthreads();
  }
  int run = (t == 0) ? 0 : part[t - 1];
  for (int i = 0; i < C; i++) {
    int idx = base + i;
    if (idx < NV) {
      offsets[idx] = run;
      cursor[idx] = run;
      run += counts[idx];
    }
  }
  if (t == 1023) offsets[NV] = run;
}

__global__ void permute_kernel(const int* __restrict__ ei, int* __restrict__ cursor,
                               int2* __restrict__ pairs) {
  int e = blockIdx.x * blockDim.x + threadIdx.x;
  if (e < NE) {
    int s = ei[e], d = ei[NE + e];
    int pos = atomicAdd(&cursor[d], 1);
    pairs[pos] = make_int2(s, d);
  }
}

// ============ edge kernel: m8n4 waves + in-block segmented scatter ============
// Block: 256 thr / 4 waves / 256 edges (dst-sorted). Wave w owns edges
// [wbase, wbase+64): full 128-feat accumulator (acc[8][4] = 128 VGPR),
// B gathered from global with 1-step double-buffer, A (weights) from global
// (L1-hot, amortized over n=4), inter-layer relu in wave-private swizzled LDS.
// Epilogue: block-local segmented reduction over LDS messages -> agg[dst]:
// complete segments = plain coalesced fp32 stores; boundary segments = atomics.
__global__ __launch_bounds__(256, 2)
void edge_kernel(const __bf16* __restrict__ hb, const int2* __restrict__ pairs,
                 const __bf16* __restrict__ w1t, const float* __restrict__ b1,
                 const __bf16* __restrict__ w2t, const float* __restrict__ b2,
                 const __bf16* __restrict__ w3t, const float* __restrict__ b3,
                 float* __restrict__ agg)
{
  __shared__ __align__(16) __bf16 M[256 * 128];
  __shared__ int sdst[256];
  __shared__ int snbr[2];
  const int t = threadIdx.x;
  const int lane = t & 63;
  const int wave = t >> 6;
  const int quad = lane >> 4;
  const int l15  = lane & 15;
  const int ebase = blockIdx.x * 256;
  const int wbase = wave * 64;

  int esrc[4], edst[4];
#pragma unroll
  for (int nt = 0; nt < 4; nt++) {
    int e = ebase + wbase + nt * 16 + l15;
    int2 pr = pairs[e];
    esrc[nt] = pr.x; edst[nt] = pr.y;
    sdst[wbase + nt * 16 + l15] = pr.y;
  }
  if (t == 0) snbr[0] = (ebase > 0) ? pairs[ebase - 1].y : -1;
  if (t == 1) snbr[1] = (ebase + 256 < NE) ? pairs[ebase + 256].y : -1;

  f32x4 acc[8][4];
#pragma unroll
  for (int mt = 0; mt < 8; mt++)
#pragma unroll
    for (int nt = 0; nt < 4; nt++)
      acc[mt][nt] = (f32x4){0.f, 0.f, 0.f, 0.f};

  // ---- layer 1: K=256, B double-buffered from global ----
  bf16x8 Bc[4], Bn[4];
#pragma unroll
  for (int nt = 0; nt < 4; nt++)
    Bc[nt] = *reinterpret_cast<const bf16x8*>(hb + (long long)esrc[nt] * 128 + quad * 8);
#pragma unroll
  for (int s = 0; s < 8; s++) {
    if (s < 7) {
      const int sn = s + 1;
#pragma unroll
      for (int nt = 0; nt < 4; nt++) {
        int row = (sn < 4) ? esrc[nt] : edst[nt];
        Bn[nt] = *reinterpret_cast<const bf16x8*>(hb + (long long)row * 128 + (sn & 3) * 32 + quad * 8);
      }
    }
    const int k = s * 32 + quad * 8;
#pragma unroll
    for (int mt = 0; mt < 8; mt++) {
      bf16x8 A = *reinterpret_cast<const bf16x8*>(w1t + (mt * 16 + l15) * 256 + k);
#pragma unroll
      for (int nt = 0; nt < 4; nt++)
        acc[mt][nt] = mfma16(A, Bc[nt], acc[mt][nt]);
    }
#pragma unroll
    for (int nt = 0; nt < 4; nt++) Bc[nt] = Bn[nt];
  }
  // epi 1: +b1, relu -> own rows (chunk XOR l15 swizzle; row&15 == l15)
#pragma unroll
  for (int mt = 0; mt < 8; mt++) {
    f32x4 bias = *reinterpret_cast<const f32x4*>(b1 + mt * 16 + quad * 4);
    const int c = (mt * 2 + (quad >> 1)) ^ l15;
#pragma unroll
    for (int nt = 0; nt < 4; nt++) {
      bf16x4 o;
#pragma unroll
      for (int r = 0; r < 4; r++) { float x = acc[mt][nt][r] + bias[r]; o[r] = (__bf16)(x > 0.f ? x : 0.f); }
      *reinterpret_cast<bf16x4*>(&M[(wbase + nt * 16 + l15) * 128 + c * 8 + (quad & 1) * 4]) = o;
      acc[mt][nt] = (f32x4){0.f, 0.f, 0.f, 0.f};
    }
  }

  // ---- layer 2: K=128, B from own LDS rows ----
#pragma unroll
  for (int s = 0; s < 4; s++) {
    bf16x8 B[4];
    const int c = (s * 4 + quad) ^ l15;
#pragma unroll
    for (int nt = 0; nt < 4; nt++)
      B[nt] = *reinterpret_cast<const bf16x8*>(&M[(wbase + nt * 16 + l15) * 128 + c * 8]);
    const int k = s * 32 + quad * 8;
#pragma unroll
    for (int mt = 0; mt < 8; mt++) {
      bf16x8 A = *reinterpret_cast<const bf16x8*>(w2t + (mt * 16 + l15) * 128 + k);
#pragma unroll
      for (int nt = 0; nt < 4; nt++)
        acc[mt][nt] = mfma16(A, B[nt], acc[mt][nt]);
    }
  }
#pragma unroll
  for (int mt = 0; mt < 8; mt++) {
    f32x4 bias = *reinterpret_cast<const f32x4*>(b2 + mt * 16 + quad * 4);
    const int c = (mt * 2 + (quad >> 1)) ^ l15;
#pragma unroll
    for (int nt = 0; nt < 4; nt++) {
      bf16x4 o;
#pragma unroll
      for (int r = 0; r < 4; r++) { float x = acc[mt][nt][r] + bias[r]; o[r] = (__bf16)(x > 0.f ? x : 0.f); }
      *reinterpret_cast<bf16x4*>(&M[(wbase + nt * 16 + l15) * 128 + c * 8 + (quad & 1) * 4]) = o;
      acc[mt][nt] = (f32x4){0.f, 0.f, 0.f, 0.f};
    }
  }

  // ---- layer 3: K=128 ----
#pragma unroll
  for (int s = 0; s < 4; s++) {
    bf16x8 B[4];
    const int c = (s * 4 + quad) ^ l15;
#pragma unroll
    for (int nt = 0; nt < 4; nt++)
      B[nt] = *reinterpret_cast<const bf16x8*>(&M[(wbase + nt * 16 + l15) * 128 + c * 8]);
    const int k = s * 32 + quad * 8;
#pragma unroll
    for (int mt = 0; mt < 8; mt++) {
      bf16x8 A = *reinterpret_cast<const bf16x8*>(w3t + (mt * 16 + l15) * 128 + k);
#pragma unroll
      for (int nt = 0; nt < 4; nt++)
        acc[mt][nt] = mfma16(A, B[nt], acc[mt][nt]);
    }
  }
  // epi 3: +b3 (no relu) -> own rows
#pragma unroll
  for (int mt = 0; mt < 8; mt++) {
    f32x4 bias = *reinterpret_cast<const f32x4*>(b3 + mt * 16 + quad * 4);
    const int c = (mt * 2 + (quad >> 1)) ^ l15;
#pragma unroll
    for (int nt = 0; nt < 4; nt++) {
      bf16x4 o;
#pragma unroll
      for (int r = 0; r < 4; r++) o[r] = (__bf16)(acc[mt][nt][r] + bias[r]);
      *reinterpret_cast<bf16x4*>(&M[(wbase + nt * 16 + l15) * 128 + c * 8 + (quad & 1) * 4]) = o;
    }
  }
  __syncthreads();   // the only barrier

  // ---- segmented reduce -> agg. thread = (feature f, row-half). dst uniform
  // across the 128 threads of a half -> uniform flushes, coalesced 512B stores.
  {
    const int f = t & 127, half = t >> 7;
    const int lo = half * 128, hi = lo + 128;
    const int cf = f >> 3, sub = f & 7;
    const int dprev = (half == 0) ? snbr[0] : sdst[127];
    const int dnext = (half == 0) ? sdst[128] : snbr[1];
    int dcur = sdst[lo];
    bool openL = (dcur == dprev);
    float a = 0.f;
    for (int r = lo; r < hi; r++) {
      int d = sdst[r];
      if (d != dcur) {
        float* p = agg + (long long)dcur * 128 + f;
        if (openL) unsafeAtomicAdd(p, a); else *p = a;
        a = 0.f; openL = false; dcur = d;
      }
      a += (float)M[r * 128 + ((cf ^ (r & 15)) * 8) + sub];
    }
    const bool openR = (dcur == dnext);
    float* p = agg + (long long)dcur * 128 + f;
    if (openL || openR) unsafeAtomicAdd(p, a); else *p = a;
  }
}

// ============ node kernel: same m8n4 shape, 2 layers, B from global ============
__global__ __launch_bounds__(256, 2)
void node_kernel(const __bf16* __restrict__ hb, const float* __restrict__ agg,
                 const __bf16* __restrict__ wn1t, const float* __restrict__ bn1,
                 const __bf16* __restrict__ wn2t, const float* __restrict__ bn2,
                 float* __restrict__ out)
{
  __shared__ __align__(16) __bf16 M[256 * 128];
  const int t = threadIdx.x;
  const int lane = t & 63;
  const int wave = t >> 6;
  const int quad = lane >> 4;
  const int l15  = lane & 15;
  const int wbase = wave * 64;
  const int nbase = blockIdx.x * 256 + wbase;

  int nid[4];
#pragma unroll
  for (int nt = 0; nt < 4; nt++) {
    int n = nbase + nt * 16 + l15;
    nid[nt] = n < NV ? n : NV - 1;
  }

  f32x4 acc[8][4];
#pragma unroll
  for (int mt = 0; mt < 8; mt++)
#pragma unroll
    for (int nt = 0; nt < 4; nt++)
      acc[mt][nt] = (f32x4){0.f, 0.f, 0.f, 0.f};

  // ---- layer 1: K=256 ([h | agg]); B dbuf; agg is fp32 -> convert ----
  bf16x8 Bc[4], Bn[4];
#pragma unroll
  for (int nt = 0; nt < 4; nt++)
    Bc[nt] = *reinterpret_cast<const bf16x8*>(hb + (long long)nid[nt] * 128 + quad * 8);
#pragma unroll
  for (int s = 0; s < 8; s++) {
    if (s < 7) {
      const int sn = s + 1;
      if (sn < 4) {
#pragma unroll
        for (int nt = 0; nt < 4; nt++)
          Bn[nt] = *reinterpret_cast<const bf16x8*>(hb + (long long)nid[nt] * 128 + sn * 32 + quad * 8);
      } else {
#pragma unroll
        for (int nt = 0; nt < 4; nt++) {
          const float* ap = agg + (long long)nid[nt] * 128 + (sn - 4) * 32 + quad * 8;
          f32x4 a0 = *reinterpret_cast<const f32x4*>(ap);
          f32x4 a1 = *reinterpret_cast<const f32x4*>(ap + 4);
          bf16x8 bb;
#pragma unroll
          for (int j = 0; j < 4; j++) { bb[j] = (__bf16)a0[j]; bb[4 + j] = (__bf16)a1[j]; }
          Bn[nt] = bb;
        }
      }
    }
    const int k = s * 32 + quad * 8;
#pragma unroll
    for (int mt = 0; mt < 8; mt++) {
      bf16x8 A = *reinterpret_cast<const bf16x8*>(wn1t + (mt * 16 + l15) * 256 + k);
#pragma unroll
      for (int nt = 0; nt < 4; nt++)
        acc[mt][nt] = mfma16(A, Bc[nt], acc[mt][nt]);
    }
#pragma unroll
    for (int nt = 0; nt < 4; nt++) Bc[nt] = Bn[nt];
  }
  // epi: +bn1, relu -> own LDS rows
#pragma unroll
  for (int mt = 0; mt < 8; mt++) {
    f32x4 bias = *reinterpret_cast<const f32x4*>(bn1 + mt * 16 + quad * 4);
    const int c = (mt * 2 + (quad >> 1)) ^ l15;
#pragma unroll
    for (int nt = 0; nt < 4; nt++) {
      bf16x4 o;
#pragma unroll
      for (int r = 0; r < 4; r++) { float x = acc[mt][nt][r] + bias[r]; o[r] = (__bf16)(x > 0.f ? x : 0.f); }
      *reinterpret_cast<bf16x4*>(&M[(wbase + nt * 16 + l15) * 128 + c * 8 + (quad & 1) * 4]) = o;
      acc[mt][nt] = (f32x4){0.f, 0.f, 0.f, 0.f};
    }
  }

  // ---- layer 2: K=128 ----
#pragma unroll
  for (int s = 0; s < 4; s++) {
    bf16x8 B[4];
    const int c = (s * 4 + quad) ^ l15;
#pragma unroll
    for (int nt = 0; nt < 4; nt++)
      B[nt] = *reinterpret_cast<const bf16x8*>(&M[(wbase + nt * 16 + l15) * 128 + c * 8]);
    const int k = s * 32 + quad * 8;
#pragma unroll
    for (int mt = 0; mt < 8; mt++) {
      bf16x8 A = *reinterpret_cast<const bf16x8*>(wn2t + (mt * 16 + l15) * 128 + k);
#pragma unroll
      for (int nt = 0; nt < 4; nt++)
        acc[mt][nt] = mfma16(A, B[nt], acc[mt][nt]);
    }
  }
  // final: +bn2, fp32 store
#pragma unroll
  for (int mt = 0; mt < 8; mt++) {
    f32x4 bias = *reinterpret_cast<const f32x4*>(bn2 + mt * 16 + quad * 4);
#pragma unroll
    for (int nt = 0; nt < 4; nt++) {
      int n = nbase + nt * 16 + l15;
      if (n < NV) {
        f32x4 v;
#pragma unroll
        for (int r = 0; r < 4; r++) v[r] = acc[mt][nt][r] + bias[r];
        *reinterpret_cast<f32x4*>(out + (long long)n * 128 + mt * 16 + quad * 4) = v;
      }
    }
  }
}

static inline size_t align16(size_t x) { return (x + 15) & ~(size_t)15; }

extern "C" void kernel_launch(void* const* d_in, const int* in_sizes, int n_in,
                              void* d_out, int out_size, void* d_ws, size_t ws_size,
                              hipStream_t stream)
{
  const float* h   = (const float*)d_in[0];
  const int*   ei  = (const int*)d_in[1];
  const float* W1  = (const float*)d_in[2];
  const float* b1  = (const float*)d_in[3];
  const float* W2  = (const float*)d_in[4];
  const float* b2  = (const float*)d_in[5];
  const float* W3  = (const float*)d_in[6];
  const float* b3  = (const float*)d_in[7];
  const float* Wn1 = (const float*)d_in[8];
  const float* bn1 = (const float*)d_in[9];
  const float* Wn2 = (const float*)d_in[10];
  const float* bn2 = (const float*)d_in[11];
  float* out = (float*)d_out;

  char* p = (char*)d_ws;
  __bf16* hb   = (__bf16*)p; p += align16((size_t)NV * 128 * 2);
  __bf16* w1t  = (__bf16*)p; p += align16(128 * 256 * 2);
  __bf16* w2t  = (__bf16*)p; p += align16(128 * 128 * 2);
  __bf16* w3t  = (__bf16*)p; p += align16(128 * 128 * 2);
  __bf16* wn1t = (__bf16*)p; p += align16(128 * 256 * 2);
  __bf16* wn2t = (__bf16*)p; p += align16(128 * 128 * 2);
  int* counts  = (int*)p; p += align16((size_t)NV * 4);
  int* offsets = (int*)p; p += align16((size_t)(NV + 1) * 4);
  int* cursor  = (int*)p; p += align16((size_t)NV * 4);
  int2* pairs  = (int2*)p; p += align16((size_t)NE * 8);
  float* agg   = (float*)p; p += align16((size_t)NV * 128 * 4);

  hipMemsetAsync(counts, 0, (size_t)NV * 4, stream);
  hipMemsetAsync(agg, 0, (size_t)NV * 128 * 4, stream);
  {
    int total = CVT_N + PW_N + NE;
    prep_kernel<<<(total + 255) / 256, 256, 0, stream>>>(
        h, hb, W1, W2, W3, Wn1, Wn2, w1t, w2t, w3t, wn1t, wn2t, ei, counts);
  }
  scan_kernel<<<1, 1024, 0, stream>>>(counts, offsets, cursor);
  permute_kernel<<<(NE + 255) / 256, 256, 0, stream>>>(ei, cursor, pairs);
  edge_kernel<<<NE / 256, 256, 0, stream>>>(hb, pairs, w1t, b1, w2t, b2, w3t, b3, agg);
  node_kernel<<<(NV + 255) / 256, 256, 0, stream>>>(hb, agg, wn1t, bn1, wn2t, bn2, out);
}

// Round 7
// 547.544 us; speedup vs baseline: 2.0950x; 1.2940x over previous
//
#include <hip/hip_runtime.h>

#define NV 50000
#define NE 800000
#define CVT_N 1600000
#define TR_N  81920
#define W3N_N 16384
#define B3N_N 128

typedef __bf16 bf16x8 __attribute__((ext_vector_type(8)));
typedef __bf16 bf16x4 __attribute__((ext_vector_type(4)));
typedef float  f32x4  __attribute__((ext_vector_type(4)));

static __device__ __forceinline__ f32x4 mfma16(bf16x8 a, bf16x8 b, f32x4 c) {
  return __builtin_amdgcn_mfma_f32_16x16x32_bf16(a, b, c, 0, 0, 0);
}

// ---- fused prep: h->bf16, 5 128x128 transposes, W3n=W3@Wn1bot fold, b3n, hist ----
__global__ void prep_kernel(const float* __restrict__ h, __bf16* __restrict__ hb,
    const float* __restrict__ W1, const float* __restrict__ W2, const float* __restrict__ W3,
    const float* __restrict__ Wn1, const float* __restrict__ Wn2, const float* __restrict__ b3,
    __bf16* __restrict__ w1st, __bf16* __restrict__ w1dt, __bf16* __restrict__ w2t,
    __bf16* __restrict__ wn1c, __bf16* __restrict__ wn2t, float* __restrict__ b3n,
    const int* __restrict__ ei, int* __restrict__ counts)
{
  int i = blockIdx.x * blockDim.x + threadIdx.x;
  if (i < CVT_N) {
    f32x4 v = reinterpret_cast<const f32x4*>(h)[i];
    bf16x4 o;
    o[0] = (__bf16)v[0]; o[1] = (__bf16)v[1]; o[2] = (__bf16)v[2]; o[3] = (__bf16)v[3];
    reinterpret_cast<bf16x4*>(hb)[i] = o;
    return;
  }
  i -= CVT_N;
  if (i < TR_N) {
    int seg = i >> 14;           // 5 blocks of 16384
    int j = i & 16383;
    int f = j >> 7, k = j & 127;
    switch (seg) {
      case 0: w1st[j] = (__bf16)W1[k * 128 + f]; break;         // W1top^T
      case 1: w1dt[j] = (__bf16)W1[(k + 128) * 128 + f]; break; // W1bot^T
      case 2: w2t[j]  = (__bf16)W2[k * 128 + f]; break;
      case 3: wn1c[f * 256 + k] = (__bf16)Wn1[k * 128 + f]; break; // Wn1top^T
      case 4: wn2t[j] = (__bf16)Wn2[k * 128 + f]; break;
    }
    return;
  }
  i -= TR_N;
  if (i < W3N_N) {   // wn1c[f][128+ii] = sum_j W3[ii][j] * Wn1[128+j][f]
    int f = i >> 7, ii = i & 127;
    float a = 0.f;
    for (int j = 0; j < 128; j++) a += W3[ii * 128 + j] * Wn1[(128 + j) * 128 + f];
    wn1c[f * 256 + 128 + ii] = (__bf16)a;
    return;
  }
  i -= W3N_N;
  if (i < B3N_N) {   // b3n[f] = sum_j b3[j] * Wn1[128+j][f]
    float a = 0.f;
    for (int j = 0; j < 128; j++) a += b3[j] * Wn1[(128 + j) * 128 + i];
    b3n[i] = a;
    return;
  }
  i -= B3N_N;
  if (i < NE) atomicAdd(&counts[ei[NE + i]], 1);
}

__global__ __launch_bounds__(1024)
void scan_kernel(const int* __restrict__ counts, int* __restrict__ offsets,
                 int* __restrict__ cursor) {
  __shared__ int part[1024];
  const int t = threadIdx.x;
  const int C = (NV + 1023) / 1024;
  const int base = t * C;
  int s = 0;
  for (int i = 0; i < C; i++) {
    int idx = base + i;
    if (idx < NV) s += counts[idx];
  }
  part[t] = s;
  __syncthreads();
  for (int off = 1; off < 1024; off <<= 1) {
    int v = 0;
    if (t >= off) v = part[t - off];
    __syncthreads();
    if (t >= off) part[t] += v;
    __syncthreads();
  }
  int run = (t == 0) ? 0 : part[t - 1];
  for (int i = 0; i < C; i++) {
    int idx = base + i;
    if (idx < NV) {
      offsets[idx] = run;
      cursor[idx] = run;
      run += counts[idx];
    }
  }
  if (t == 1023) offsets[NV] = run;
}

__global__ void permute_kernel(const int* __restrict__ ei, int* __restrict__ cursor,
                               int2* __restrict__ pairs) {
  int e = blockIdx.x * blockDim.x + threadIdx.x;
  if (e < NE) {
    int s = ei[e], d = ei[NE + e];
    int pos = atomicAdd(&cursor[d], 1);
    pairs[pos] = make_int2(s, d);
  }
}

// ---- one K=128 GEMM (64 rows x 128 feats per wave), B rows from global ----
static __device__ __forceinline__ void gemm128_rows(
    const __bf16* __restrict__ hb, const int* nid, const __bf16* __restrict__ At,
    const float* __restrict__ bias, __bf16* __restrict__ Out,
    int nbase, int l15, int quad)
{
  f32x4 acc[8][4];
#pragma unroll
  for (int mt = 0; mt < 8; mt++)
#pragma unroll
    for (int nt = 0; nt < 4; nt++)
      acc[mt][nt] = (f32x4){0.f, 0.f, 0.f, 0.f};

  bf16x8 Bc[4], Bn[4];
#pragma unroll
  for (int nt = 0; nt < 4; nt++)
    Bc[nt] = *reinterpret_cast<const bf16x8*>(hb + (long long)nid[nt] * 128 + quad * 8);
#pragma unroll
  for (int s = 0; s < 4; s++) {
    if (s < 3) {
#pragma unroll
      for (int nt = 0; nt < 4; nt++)
        Bn[nt] = *reinterpret_cast<const bf16x8*>(hb + (long long)nid[nt] * 128 + (s + 1) * 32 + quad * 8);
    }
    const int k = s * 32 + quad * 8;
#pragma unroll
    for (int mt = 0; mt < 8; mt++) {
      bf16x8 A = *reinterpret_cast<const bf16x8*>(At + (mt * 16 + l15) * 128 + k);
#pragma unroll
      for (int nt = 0; nt < 4; nt++)
        acc[mt][nt] = mfma16(A, Bc[nt], acc[mt][nt]);
    }
#pragma unroll
    for (int nt = 0; nt < 4; nt++) Bc[nt] = Bn[nt];
  }
#pragma unroll
  for (int mt = 0; mt < 8; mt++) {
    f32x4 bb = bias ? *reinterpret_cast<const f32x4*>(bias + mt * 16 + quad * 4)
                    : (f32x4){0.f, 0.f, 0.f, 0.f};
#pragma unroll
    for (int nt = 0; nt < 4; nt++) {
      int n = nbase + nt * 16 + l15;
      if (n < NV) {
        bf16x4 o;
#pragma unroll
        for (int r = 0; r < 4; r++) o[r] = (__bf16)(acc[mt][nt][r] + bb[r]);
        *reinterpret_cast<bf16x4*>(Out + (long long)n * 128 + mt * 16 + quad * 4) = o;
      }
    }
  }
}

// ---- H1s = h@W1top ; H1d = h@W1bot + b1 (dense, 256 nodes/block) ----
__global__ __launch_bounds__(256, 2)
void h1_kernel(const __bf16* __restrict__ hb, const float* __restrict__ b1,
               const __bf16* __restrict__ w1st, const __bf16* __restrict__ w1dt,
               __bf16* __restrict__ H1s, __bf16* __restrict__ H1d)
{
  const int t = threadIdx.x;
  const int lane = t & 63, wave = t >> 6;
  const int quad = lane >> 4, l15 = lane & 15;
  const int nbase = blockIdx.x * 256 + wave * 64;
  int nid[4];
#pragma unroll
  for (int nt = 0; nt < 4; nt++) {
    int n = nbase + nt * 16 + l15;
    nid[nt] = n < NV ? n : NV - 1;
  }
  gemm128_rows(hb, nid, w1st, nullptr, H1s, nbase, l15, quad);
  gemm128_rows(hb, nid, w1dt, b1, H1d, nbase, l15, quad);
}

// ============ edge kernel: gather-add-relu -> K=128 GEMM -> segmented reduce ============
// Block: 256 thr / 4 waves / 256 edges (dst-sorted).
// P1: all threads build m1[256][128] in LDS = relu(H1s[src]+H1d[dst]) (coalesced
//     256B row bursts; XOR-16 chunk swizzle). P2: wave w = 64 edges x 128 feats
//     (acc 128 VGPR), A=w2t (L1-hot), B from LDS; epi relu -> m2 overwrites m1.
// P3: r6-proven segmented reduction -> agg2 (plain stores interior, atomics at
//     block boundaries).
__global__ __launch_bounds__(256, 2)
void edge_kernel(const __bf16* __restrict__ H1s, const __bf16* __restrict__ H1d,
                 const int2* __restrict__ pairs,
                 const __bf16* __restrict__ w2t, const float* __restrict__ b2,
                 float* __restrict__ agg2)
{
  __shared__ __align__(16) __bf16 M1[256 * 128];
  __shared__ int ssrc[256], sdst[256];
  __shared__ int snbr[2];
  const int t = threadIdx.x;
  const int lane = t & 63, wave = t >> 6;
  const int quad = lane >> 4, l15 = lane & 15;
  const int ebase = blockIdx.x * 256;

  {
    int2 pr = pairs[ebase + t];
    ssrc[t] = pr.x; sdst[t] = pr.y;
    if (t == 0) snbr[0] = (ebase > 0) ? pairs[ebase - 1].y : -1;
    if (t == 1) snbr[1] = (ebase + 256 < NE) ? pairs[ebase + 256].y : -1;
  }
  __syncthreads();

  // ---- P1: m1 = relu(H1s[src] + H1d[dst]) -> LDS (4096 16B items) ----
#pragma unroll
  for (int it = 0; it < 16; it++) {
    int g = it * 256 + t;
    int e = g >> 4, c8 = g & 15;
    bf16x8 a = *reinterpret_cast<const bf16x8*>(H1s + (long long)ssrc[e] * 128 + c8 * 8);
    bf16x8 b = *reinterpret_cast<const bf16x8*>(H1d + (long long)sdst[e] * 128 + c8 * 8);
    bf16x8 o;
#pragma unroll
    for (int j = 0; j < 8; j++) {
      float x = (float)a[j] + (float)b[j];
      o[j] = (__bf16)(x > 0.f ? x : 0.f);
    }
    *reinterpret_cast<bf16x8*>(&M1[e * 128 + ((c8 ^ (e & 15)) * 8)]) = o;
  }
  __syncthreads();

  // ---- P2: m2 = relu(m1 @ W2 + b2), wave-private 64 rows ----
  const int wbase = wave * 64;
  f32x4 acc[8][4];
#pragma unroll
  for (int mt = 0; mt < 8; mt++)
#pragma unroll
    for (int nt = 0; nt < 4; nt++)
      acc[mt][nt] = (f32x4){0.f, 0.f, 0.f, 0.f};

#pragma unroll
  for (int s = 0; s < 4; s++) {
    bf16x8 B[4];
#pragma unroll
    for (int nt = 0; nt < 4; nt++) {
      int row = wbase + nt * 16 + l15;
      B[nt] = *reinterpret_cast<const bf16x8*>(&M1[row * 128 + (((4 * s + quad) ^ (row & 15)) * 8)]);
    }
    const int k = s * 32 + quad * 8;
#pragma unroll
    for (int mt = 0; mt < 8; mt++) {
      bf16x8 A = *reinterpret_cast<const bf16x8*>(w2t + (mt * 16 + l15) * 128 + k);
#pragma unroll
      for (int nt = 0; nt < 4; nt++)
        acc[mt][nt] = mfma16(A, B[nt], acc[mt][nt]);
    }
  }
#pragma unroll
  for (int mt = 0; mt < 8; mt++) {
    f32x4 bias = *reinterpret_cast<const f32x4*>(b2 + mt * 16 + quad * 4);
#pragma unroll
    for (int nt = 0; nt < 4; nt++) {
      int row = wbase + nt * 16 + l15;
      int c = (2 * mt + (quad >> 1)) ^ (row & 15);
      bf16x4 o;
#pragma unroll
      for (int r = 0; r < 4; r++) {
        float x = acc[mt][nt][r] + bias[r];
        o[r] = (__bf16)(x > 0.f ? x : 0.f);
      }
      *reinterpret_cast<bf16x4*>(&M1[row * 128 + c * 8 + (quad & 1) * 4]) = o;
    }
  }
  __syncthreads();

  // ---- P3: segmented reduce over 256 dst-sorted rows -> agg2 ----
  {
    const int f = t & 127, half = t >> 7;
    const int lo = half * 128, hi = lo + 128;
    const int cf = f >> 3, sub = f & 7;
    const int dprev = half ? sdst[127] : snbr[0];
    const int dnext = half ? snbr[1] : sdst[128];
    int dcur = sdst[lo];
    bool openL = (dcur == dprev);
    float a = 0.f;
    for (int r = lo; r < hi; r++) {
      int d = sdst[r];
      if (d != dcur) {
        float* p = agg2 + (long long)dcur * 128 + f;
        if (openL) unsafeAtomicAdd(p, a); else *p = a;
        a = 0.f; openL = false; dcur = d;
      }
      a += (float)M1[r * 128 + ((cf ^ (r & 15)) * 8) + sub];
    }
    const bool openR = (dcur == dnext);
    float* p = agg2 + (long long)dcur * 128 + f;
    if (openL || openR) unsafeAtomicAdd(p, a); else *p = a;
  }
}

// ============ node kernel: x1 = relu(h@Wn1top + agg2@W3n + bn1 + cnt*b3n); out = x1@Wn2 + bn2 ============
__global__ __launch_bounds__(256, 2)
void node_kernel(const __bf16* __restrict__ hb, const float* __restrict__ agg2,
                 const int* __restrict__ offsets,
                 const __bf16* __restrict__ wn1c, const float* __restrict__ bn1,
                 const float* __restrict__ b3n,
                 const __bf16* __restrict__ wn2t, const float* __restrict__ bn2,
                 float* __restrict__ out)
{
  __shared__ __align__(16) __bf16 M[256 * 128];
  const int t = threadIdx.x;
  const int lane = t & 63, wave = t >> 6;
  const int quad = lane >> 4, l15 = lane & 15;
  const int wbase = wave * 64;
  const int nbase = blockIdx.x * 256 + wbase;

  int nid[4]; float fcnt[4];
#pragma unroll
  for (int nt = 0; nt < 4; nt++) {
    int n = nbase + nt * 16 + l15;
    nid[nt] = n < NV ? n : NV - 1;
    fcnt[nt] = (n < NV) ? (float)(offsets[n + 1] - offsets[n]) : 0.f;
  }

  f32x4 acc[8][4];
#pragma unroll
  for (int mt = 0; mt < 8; mt++)
#pragma unroll
    for (int nt = 0; nt < 4; nt++)
      acc[mt][nt] = (f32x4){0.f, 0.f, 0.f, 0.f};

  // ---- layer 1: K=256 over [hb | agg2]; B dbuf ----
  bf16x8 Bc[4], Bn[4];
#pragma unroll
  for (int nt = 0; nt < 4; nt++)
    Bc[nt] = *reinterpret_cast<const bf16x8*>(hb + (long long)nid[nt] * 128 + quad * 8);
#pragma unroll
  for (int s = 0; s < 8; s++) {
    if (s < 7) {
      const int sn = s + 1;
      if (sn < 4) {
#pragma unroll
        for (int nt = 0; nt < 4; nt++)
          Bn[nt] = *reinterpret_cast<const bf16x8*>(hb + (long long)nid[nt] * 128 + sn * 32 + quad * 8);
      } else {
#pragma unroll
        for (int nt = 0; nt < 4; nt++) {
          const float* ap = agg2 + (long long)nid[nt] * 128 + (sn - 4) * 32 + quad * 8;
          f32x4 a0 = *reinterpret_cast<const f32x4*>(ap);
          f32x4 a1 = *reinterpret_cast<const f32x4*>(ap + 4);
          bf16x8 bb;
#pragma unroll
          for (int j = 0; j < 4; j++) { bb[j] = (__bf16)a0[j]; bb[4 + j] = (__bf16)a1[j]; }
          Bn[nt] = bb;
        }
      }
    }
    const int k = s * 32 + quad * 8;
#pragma unroll
    for (int mt = 0; mt < 8; mt++) {
      bf16x8 A = *reinterpret_cast<const bf16x8*>(wn1c + (mt * 16 + l15) * 256 + k);
#pragma unroll
      for (int nt = 0; nt < 4; nt++)
        acc[mt][nt] = mfma16(A, Bc[nt], acc[mt][nt]);
    }
#pragma unroll
    for (int nt = 0; nt < 4; nt++) Bc[nt] = Bn[nt];
  }
  // epi: + bn1 + cnt*b3n, relu -> wave-private LDS rows (no barrier needed)
#pragma unroll
  for (int mt = 0; mt < 8; mt++) {
    f32x4 bb  = *reinterpret_cast<const f32x4*>(bn1 + mt * 16 + quad * 4);
    f32x4 b3c = *reinterpret_cast<const f32x4*>(b3n + mt * 16 + quad * 4);
#pragma unroll
    for (int nt = 0; nt < 4; nt++) {
      int row = wbase + nt * 16 + l15;
      int c = (2 * mt + (quad >> 1)) ^ (row & 15);
      bf16x4 o;
#pragma unroll
      for (int r = 0; r < 4; r++) {
        float x = acc[mt][nt][r] + bb[r] + fcnt[nt] * b3c[r];
        o[r] = (__bf16)(x > 0.f ? x : 0.f);
      }
      *reinterpret_cast<bf16x4*>(&M[row * 128 + c * 8 + (quad & 1) * 4]) = o;
      acc[mt][nt] = (f32x4){0.f, 0.f, 0.f, 0.f};
    }
  }

  // ---- layer 2: K=128 from LDS ----
#pragma unroll
  for (int s = 0; s < 4; s++) {
    bf16x8 B[4];
#pragma unroll
    for (int nt = 0; nt < 4; nt++) {
      int row = wbase + nt * 16 + l15;
      B[nt] = *reinterpret_cast<const bf16x8*>(&M[row * 128 + (((4 * s + quad) ^ (row & 15)) * 8)]);
    }
    const int k = s * 32 + quad * 8;
#pragma unroll
    for (int mt = 0; mt < 8; mt++) {
      bf16x8 A = *reinterpret_cast<const bf16x8*>(wn2t + (mt * 16 + l15) * 128 + k);
#pragma unroll
      for (int nt = 0; nt < 4; nt++)
        acc[mt][nt] = mfma16(A, B[nt], acc[mt][nt]);
    }
  }
#pragma unroll
  for (int mt = 0; mt < 8; mt++) {
    f32x4 bias = *reinterpret_cast<const f32x4*>(bn2 + mt * 16 + quad * 4);
#pragma unroll
    for (int nt = 0; nt < 4; nt++) {
      int n = nbase + nt * 16 + l15;
      if (n < NV) {
        f32x4 v;
#pragma unroll
        for (int r = 0; r < 4; r++) v[r] = acc[mt][nt][r] + bias[r];
        *reinterpret_cast<f32x4*>(out + (long long)n * 128 + mt * 16 + quad * 4) = v;
      }
    }
  }
}

static inline size_t align16(size_t x) { return (x + 15) & ~(size_t)15; }

extern "C" void kernel_launch(void* const* d_in, const int* in_sizes, int n_in,
                              void* d_out, int out_size, void* d_ws, size_t ws_size,
                              hipStream_t stream)
{
  const float* h   = (const float*)d_in[0];
  const int*   ei  = (const int*)d_in[1];
  const float* W1  = (const float*)d_in[2];
  const float* b1  = (const float*)d_in[3];
  const float* W2  = (const float*)d_in[4];
  const float* b2  = (const float*)d_in[5];
  const float* W3  = (const float*)d_in[6];
  const float* b3  = (const float*)d_in[7];
  const float* Wn1 = (const float*)d_in[8];
  const float* bn1 = (const float*)d_in[9];
  const float* Wn2 = (const float*)d_in[10];
  const float* bn2 = (const float*)d_in[11];
  float* out = (float*)d_out;

  char* p = (char*)d_ws;
  __bf16* hb   = (__bf16*)p; p += align16((size_t)NV * 128 * 2);
  __bf16* H1s  = (__bf16*)p; p += align16((size_t)NV * 128 * 2);
  __bf16* H1d  = (__bf16*)p; p += align16((size_t)NV * 128 * 2);
  __bf16* w1st = (__bf16*)p; p += align16(128 * 128 * 2);
  __bf16* w1dt = (__bf16*)p; p += align16(128 * 128 * 2);
  __bf16* w2t  = (__bf16*)p; p += align16(128 * 128 * 2);
  __bf16* wn1c = (__bf16*)p; p += align16(128 * 256 * 2);
  __bf16* wn2t = (__bf16*)p; p += align16(128 * 128 * 2);
  float*  b3n  = (float*)p;  p += align16(128 * 4);
  int* counts  = (int*)p; p += align16((size_t)NV * 4);
  int* offsets = (int*)p; p += align16((size_t)(NV + 1) * 4);
  int* cursor  = (int*)p; p += align16((size_t)NV * 4);
  int2* pairs  = (int2*)p; p += align16((size_t)NE * 8);
  float* agg2  = (float*)p; p += align16((size_t)NV * 128 * 4);

  hipMemsetAsync(counts, 0, (size_t)NV * 4, stream);
  hipMemsetAsync(agg2, 0, (size_t)NV * 128 * 4, stream);
  {
    int total = CVT_N + TR_N + W3N_N + B3N_N + NE;
    prep_kernel<<<(total + 255) / 256, 256, 0, stream>>>(
        h, hb, W1, W2, W3, Wn1, Wn2, b3,
        w1st, w1dt, w2t, wn1c, wn2t, b3n, ei, counts);
  }
  scan_kernel<<<1, 1024, 0, stream>>>(counts, offsets, cursor);
  permute_kernel<<<(NE + 255) / 256, 256, 0, stream>>>(ei, cursor, pairs);
  h1_kernel<<<(NV + 255) / 256, 256, 0, stream>>>(hb, b1, w1st, w1dt, H1s, H1d);
  edge_kernel<<<NE / 256, 256, 0, stream>>>(H1s, H1d, pairs, w2t, b2, agg2);
  node_kernel<<<(NV + 255) / 256, 256, 0, stream>>>(hb, agg2, offsets, wn1c, bn1, b3n,
                                                    wn2t, bn2, out);
}

// Round 8
// 417.702 us; speedup vs baseline: 2.7463x; 1.3109x over previous
//
#include <hip/hip_runtime.h>

#define NV 50000
#define NE 800000
#define CVT_N 1600000
#define TR_N  81920
#define W3N_N 16384
#define B3N_N 128
#define NB1 49   // ceil(NV/1024)

typedef _Float16 f16x8 __attribute__((ext_vector_type(8)));
typedef _Float16 f16x4 __attribute__((ext_vector_type(4)));
typedef float    f32x4 __attribute__((ext_vector_type(4)));

static __device__ __forceinline__ f32x4 mfma16(f16x8 a, f16x8 b, f32x4 c) {
  return __builtin_amdgcn_mfma_f32_16x16x32_f16(a, b, c, 0, 0, 0);
}

// ---- fused prep: h->f16, 5 128x128 transposes (f16), W3n fold, b3n, hist ----
__global__ void prep_kernel(const float* __restrict__ h, _Float16* __restrict__ hf,
    const float* __restrict__ W1, const float* __restrict__ W2, const float* __restrict__ W3,
    const float* __restrict__ Wn1, const float* __restrict__ Wn2, const float* __restrict__ b3,
    _Float16* __restrict__ w1st, _Float16* __restrict__ w1dt, _Float16* __restrict__ w2t,
    _Float16* __restrict__ wn1c, _Float16* __restrict__ wn2t, float* __restrict__ b3n,
    const int* __restrict__ ei, int* __restrict__ counts)
{
  int i = blockIdx.x * blockDim.x + threadIdx.x;
  if (i < CVT_N) {
    f32x4 v = reinterpret_cast<const f32x4*>(h)[i];
    f16x4 o;
    o[0] = (_Float16)v[0]; o[1] = (_Float16)v[1]; o[2] = (_Float16)v[2]; o[3] = (_Float16)v[3];
    reinterpret_cast<f16x4*>(hf)[i] = o;
    return;
  }
  i -= CVT_N;
  if (i < TR_N) {
    int seg = i >> 14;
    int j = i & 16383;
    int f = j >> 7, k = j & 127;
    switch (seg) {
      case 0: w1st[j] = (_Float16)W1[k * 128 + f]; break;         // W1top^T
      case 1: w1dt[j] = (_Float16)W1[(k + 128) * 128 + f]; break; // W1bot^T
      case 2: w2t[j]  = (_Float16)W2[k * 128 + f]; break;
      case 3: wn1c[f * 256 + k] = (_Float16)Wn1[k * 128 + f]; break;
      case 4: wn2t[j] = (_Float16)Wn2[k * 128 + f]; break;
    }
    return;
  }
  i -= TR_N;
  if (i < W3N_N) {   // wn1c[f][128+ii] = sum_j W3[ii][j] * Wn1[128+j][f]
    int f = i >> 7, ii = i & 127;
    float a = 0.f;
    for (int j = 0; j < 128; j++) a += W3[ii * 128 + j] * Wn1[(128 + j) * 128 + f];
    wn1c[f * 256 + 128 + ii] = (_Float16)a;
    return;
  }
  i -= W3N_N;
  if (i < B3N_N) {
    float a = 0.f;
    for (int j = 0; j < 128; j++) a += b3[j] * Wn1[(128 + j) * 128 + i];
    b3n[i] = a;
    return;
  }
  i -= B3N_N;
  if (i < NE) atomicAdd(&counts[ei[NE + i]], 1);
}

// ---- parallel scan: block sums -> tiny scan -> block-local scan ----
__global__ __launch_bounds__(1024)
void bsum_kernel(const int* __restrict__ counts, int* __restrict__ bsum) {
  __shared__ int red[1024];
  const int t = threadIdx.x;
  int i = blockIdx.x * 1024 + t;
  red[t] = (i < NV) ? counts[i] : 0;
  __syncthreads();
  for (int off = 512; off > 0; off >>= 1) {
    if (t < off) red[t] += red[t + off];
    __syncthreads();
  }
  if (t == 0) bsum[blockIdx.x] = red[0];
}

__global__ void bscan_kernel(const int* __restrict__ bsum, int* __restrict__ boff) {
  if (threadIdx.x == 0 && blockIdx.x == 0) {
    int run = 0;
    for (int b = 0; b < NB1; b++) { boff[b] = run; run += bsum[b]; }
    boff[NB1] = run;
  }
}

__global__ __launch_bounds__(1024)
void offs_kernel(const int* __restrict__ counts, const int* __restrict__ boff,
                 int* __restrict__ offsets, int* __restrict__ cursor) {
  __shared__ int s[1024];
  const int t = threadIdx.x;
  int i = blockIdx.x * 1024 + t;
  int v = (i < NV) ? counts[i] : 0;
  s[t] = v;
  __syncthreads();
  for (int off = 1; off < 1024; off <<= 1) {
    int x = (t >= off) ? s[t - off] : 0;
    __syncthreads();
    s[t] += x;
    __syncthreads();
  }
  if (i < NV) {
    int excl = boff[blockIdx.x] + s[t] - v;
    offsets[i] = excl;
    cursor[i] = excl;
    if (i == NV - 1) offsets[NV] = boff[blockIdx.x] + s[t];
  }
}

__global__ void permute_kernel(const int* __restrict__ ei, int* __restrict__ cursor,
                               int2* __restrict__ pairs) {
  int e = blockIdx.x * blockDim.x + threadIdx.x;
  if (e < NE) {
    int s = ei[e], d = ei[NE + e];
    int pos = atomicAdd(&cursor[d], 1);
    pairs[pos] = make_int2(s, d);
  }
}

// ---- one K=128 GEMM (64 rows x 128 feats per wave), f16 ----
static __device__ __forceinline__ void gemm128_rows(
    const _Float16* __restrict__ hf, const int* nid, const _Float16* __restrict__ At,
    const float* __restrict__ bias, _Float16* __restrict__ Out,
    int nbase, int l15, int quad)
{
  f32x4 acc[8][4];
#pragma unroll
  for (int mt = 0; mt < 8; mt++)
#pragma unroll
    for (int nt = 0; nt < 4; nt++)
      acc[mt][nt] = (f32x4){0.f, 0.f, 0.f, 0.f};

  f16x8 Bc[4], Bn[4];
#pragma unroll
  for (int nt = 0; nt < 4; nt++)
    Bc[nt] = *reinterpret_cast<const f16x8*>(hf + (long long)nid[nt] * 128 + quad * 8);
#pragma unroll
  for (int s = 0; s < 4; s++) {
    if (s < 3) {
#pragma unroll
      for (int nt = 0; nt < 4; nt++)
        Bn[nt] = *reinterpret_cast<const f16x8*>(hf + (long long)nid[nt] * 128 + (s + 1) * 32 + quad * 8);
    }
    const int k = s * 32 + quad * 8;
#pragma unroll
    for (int mt = 0; mt < 8; mt++) {
      f16x8 A = *reinterpret_cast<const f16x8*>(At + (mt * 16 + l15) * 128 + k);
#pragma unroll
      for (int nt = 0; nt < 4; nt++)
        acc[mt][nt] = mfma16(A, Bc[nt], acc[mt][nt]);
    }
#pragma unroll
    for (int nt = 0; nt < 4; nt++) Bc[nt] = Bn[nt];
  }
#pragma unroll
  for (int mt = 0; mt < 8; mt++) {
    f32x4 bb = bias ? *reinterpret_cast<const f32x4*>(bias + mt * 16 + quad * 4)
                    : (f32x4){0.f, 0.f, 0.f, 0.f};
#pragma unroll
    for (int nt = 0; nt < 4; nt++) {
      int n = nbase + nt * 16 + l15;
      if (n < NV) {
        f16x4 o;
#pragma unroll
        for (int r = 0; r < 4; r++) o[r] = (_Float16)(acc[mt][nt][r] + bb[r]);
        *reinterpret_cast<f16x4*>(Out + (long long)n * 128 + mt * 16 + quad * 4) = o;
      }
    }
  }
}

// ---- H1s = h@W1top (y=0); H1d = h@W1bot + b1 (y=1) ----
__global__ __launch_bounds__(256, 2)
void h1_kernel(const _Float16* __restrict__ hf, const float* __restrict__ b1,
               const _Float16* __restrict__ w1st, const _Float16* __restrict__ w1dt,
               _Float16* __restrict__ H1s, _Float16* __restrict__ H1d)
{
  const int t = threadIdx.x;
  const int lane = t & 63, wave = t >> 6;
  const int quad = lane >> 4, l15 = lane & 15;
  const int nbase = blockIdx.x * 256 + wave * 64;
  int nid[4];
#pragma unroll
  for (int nt = 0; nt < 4; nt++) {
    int n = nbase + nt * 16 + l15;
    nid[nt] = n < NV ? n : NV - 1;
  }
  if (blockIdx.y == 0) gemm128_rows(hf, nid, w1st, nullptr, H1s, nbase, l15, quad);
  else                 gemm128_rows(hf, nid, w1dt, b1,      H1d, nbase, l15, quad);
}

// ============ edge kernel: 128 edges / 2 waves, m1 in registers ============
// P1: each thread builds its own B-fragments m1f[nt][s] = relu(H1s[src]+H1d[dst])
//     with packed f16 ops (no LDS, no barrier). P2: wave = 64 edges x 128 feats,
//     A=w2t (L1-hot), B=m1f regs; epi relu -> M2 LDS (f16, XOR-16 swizzle).
// P3 (after the single barrier): segmented reduce over 128 dst-sorted rows ->
//     agg2 (plain coalesced stores interior, atomics at block boundaries).
__global__ __launch_bounds__(128, 2)
void edge_kernel(const _Float16* __restrict__ H1s, const _Float16* __restrict__ H1d,
                 const int2* __restrict__ pairs,
                 const _Float16* __restrict__ w2t, const float* __restrict__ b2,
                 float* __restrict__ agg2)
{
  __shared__ __align__(16) _Float16 M2[128 * 128];
  __shared__ int sdst[128];
  __shared__ int snbr[2];
  const int t = threadIdx.x;
  const int lane = t & 63, wave = t >> 6;
  const int quad = lane >> 4, l15 = lane & 15;
  const int ebase = blockIdx.x * 128;
  const int wbase = wave * 64;

  { int2 pr = pairs[ebase + t]; sdst[t] = pr.y; }
  if (t == 0) snbr[0] = (ebase > 0) ? pairs[ebase - 1].y : -1;
  if (t == 1) snbr[1] = (ebase + 128 < NE) ? pairs[ebase + 128].y : -1;

  int esrc[4], edst[4];
#pragma unroll
  for (int nt = 0; nt < 4; nt++) {
    int2 pr = pairs[ebase + wbase + nt * 16 + l15];
    esrc[nt] = pr.x; edst[nt] = pr.y;
  }

  // ---- P1: m1 B-fragments in registers (packed f16 add+relu) ----
  f16x8 m1f[4][4];
#pragma unroll
  for (int nt = 0; nt < 4; nt++) {
#pragma unroll
    for (int s = 0; s < 4; s++) {
      f16x8 a = *reinterpret_cast<const f16x8*>(H1s + (long long)esrc[nt] * 128 + s * 32 + quad * 8);
      f16x8 b = *reinterpret_cast<const f16x8*>(H1d + (long long)edst[nt] * 128 + s * 32 + quad * 8);
      f16x8 o = a + b;
#pragma unroll
      for (int j = 0; j < 8; j++) o[j] = o[j] > (_Float16)0 ? o[j] : (_Float16)0;
      m1f[nt][s] = o;
    }
  }

  // ---- P2: m2 = relu(m1 @ W2 + b2) ----
  f32x4 acc[8][4];
#pragma unroll
  for (int mt = 0; mt < 8; mt++)
#pragma unroll
    for (int nt = 0; nt < 4; nt++)
      acc[mt][nt] = (f32x4){0.f, 0.f, 0.f, 0.f};

#pragma unroll
  for (int s = 0; s < 4; s++) {
    const int k = s * 32 + quad * 8;
#pragma unroll
    for (int mt = 0; mt < 8; mt++) {
      f16x8 A = *reinterpret_cast<const f16x8*>(w2t + (mt * 16 + l15) * 128 + k);
#pragma unroll
      for (int nt = 0; nt < 4; nt++)
        acc[mt][nt] = mfma16(A, m1f[nt][s], acc[mt][nt]);
    }
  }
#pragma unroll
  for (int mt = 0; mt < 8; mt++) {
    f32x4 bias = *reinterpret_cast<const f32x4*>(b2 + mt * 16 + quad * 4);
    const int cbase = 2 * mt + (quad >> 1);
#pragma unroll
    for (int nt = 0; nt < 4; nt++) {
      int row = wbase + nt * 16 + l15;
      int c = cbase ^ (row & 15);
      f16x4 o;
#pragma unroll
      for (int r = 0; r < 4; r++) {
        float x = acc[mt][nt][r] + bias[r];
        o[r] = (_Float16)(x > 0.f ? x : 0.f);
      }
      *reinterpret_cast<f16x4*>(&M2[row * 128 + c * 8 + (quad & 1) * 4]) = o;
    }
  }
  __syncthreads();   // the only barrier

  // ---- P3: thread t = feature, segmented reduce over 128 rows ----
  {
    const int f = t;
    const int cf = f >> 3, sub = f & 7;
    int dcur = sdst[0];
    bool openL = (dcur == snbr[0]);
    float a = 0.f;
    for (int r = 0; r < 128; r++) {
      int d = sdst[r];
      if (d != dcur) {
        float* p = agg2 + (long long)dcur * 128 + f;
        if (openL) unsafeAtomicAdd(p, a); else *p = a;
        a = 0.f; openL = false; dcur = d;
      }
      a += (float)M2[r * 128 + ((cf ^ (r & 15)) * 8) + sub];
    }
    float* p = agg2 + (long long)dcur * 128 + f;
    if (openL || (dcur == snbr[1])) unsafeAtomicAdd(p, a); else *p = a;
  }
}

// ============ node kernel: x1 = relu(h@Wn1top + agg2@W3n + bn1 + cnt*b3n); out = x1@Wn2 + bn2 ============
__global__ __launch_bounds__(256, 2)
void node_kernel(const _Float16* __restrict__ hf, const float* __restrict__ agg2,
                 const int* __restrict__ offsets,
                 const _Float16* __restrict__ wn1c, const float* __restrict__ bn1,
                 const float* __restrict__ b3n,
                 const _Float16* __restrict__ wn2t, const float* __restrict__ bn2,
                 float* __restrict__ out)
{
  __shared__ __align__(16) _Float16 M[256 * 128];
  const int t = threadIdx.x;
  const int lane = t & 63, wave = t >> 6;
  const int quad = lane >> 4, l15 = lane & 15;
  const int wbase = wave * 64;
  const int nbase = blockIdx.x * 256 + wbase;

  int nid[4]; float fcnt[4];
#pragma unroll
  for (int nt = 0; nt < 4; nt++) {
    int n = nbase + nt * 16 + l15;
    nid[nt] = n < NV ? n : NV - 1;
    fcnt[nt] = (n < NV) ? (float)(offsets[n + 1] - offsets[n]) : 0.f;
  }

  f32x4 acc[8][4];
#pragma unroll
  for (int mt = 0; mt < 8; mt++)
#pragma unroll
    for (int nt = 0; nt < 4; nt++)
      acc[mt][nt] = (f32x4){0.f, 0.f, 0.f, 0.f};

  // ---- layer 1: K=256 over [hf | agg2]; B dbuf ----
  f16x8 Bc[4], Bn[4];
#pragma unroll
  for (int nt = 0; nt < 4; nt++)
    Bc[nt] = *reinterpret_cast<const f16x8*>(hf + (long long)nid[nt] * 128 + quad * 8);
#pragma unroll
  for (int s = 0; s < 8; s++) {
    if (s < 7) {
      const int sn = s + 1;
      if (sn < 4) {
#pragma unroll
        for (int nt = 0; nt < 4; nt++)
          Bn[nt] = *reinterpret_cast<const f16x8*>(hf + (long long)nid[nt] * 128 + sn * 32 + quad * 8);
      } else {
#pragma unroll
        for (int nt = 0; nt < 4; nt++) {
          const float* ap = agg2 + (long long)nid[nt] * 128 + (sn - 4) * 32 + quad * 8;
          f32x4 a0 = *reinterpret_cast<const f32x4*>(ap);
          f32x4 a1 = *reinterpret_cast<const f32x4*>(ap + 4);
          f16x8 bb;
#pragma unroll
          for (int j = 0; j < 4; j++) { bb[j] = (_Float16)a0[j]; bb[4 + j] = (_Float16)a1[j]; }
          Bn[nt] = bb;
        }
      }
    }
    const int k = s * 32 + quad * 8;
#pragma unroll
    for (int mt = 0; mt < 8; mt++) {
      f16x8 A = *reinterpret_cast<const f16x8*>(wn1c + (mt * 16 + l15) * 256 + k);
#pragma unroll
      for (int nt = 0; nt < 4; nt++)
        acc[mt][nt] = mfma16(A, Bc[nt], acc[mt][nt]);
    }
#pragma unroll
    for (int nt = 0; nt < 4; nt++) Bc[nt] = Bn[nt];
  }
  // epi: + bn1 + cnt*b3n, relu -> wave-private LDS rows
#pragma unroll
  for (int mt = 0; mt < 8; mt++) {
    f32x4 bb  = *reinterpret_cast<const f32x4*>(bn1 + mt * 16 + quad * 4);
    f32x4 b3c = *reinterpret_cast<const f32x4*>(b3n + mt * 16 + quad * 4);
    const int cbase = 2 * mt + (quad >> 1);
#pragma unroll
    for (int nt = 0; nt < 4; nt++) {
      int row = wbase + nt * 16 + l15;
      int c = cbase ^ (row & 15);
      f16x4 o;
#pragma unroll
      for (int r = 0; r < 4; r++) {
        float x = acc[mt][nt][r] + bb[r] + fcnt[nt] * b3c[r];
        o[r] = (_Float16)(x > 0.f ? x : 0.f);
      }
      *reinterpret_cast<f16x4*>(&M[row * 128 + c * 8 + (quad & 1) * 4]) = o;
      acc[mt][nt] = (f32x4){0.f, 0.f, 0.f, 0.f};
    }
  }

  // ---- layer 2: K=128 from LDS (wave-private rows, no barrier) ----
#pragma unroll
  for (int s = 0; s < 4; s++) {
    f16x8 B[4];
#pragma unroll
    for (int nt = 0; nt < 4; nt++) {
      int row = wbase + nt * 16 + l15;
      B[nt] = *reinterpret_cast<const f16x8*>(&M[row * 128 + (((4 * s + quad) ^ (row & 15)) * 8)]);
    }
    const int k = s * 32 + quad * 8;
#pragma unroll
    for (int mt = 0; mt < 8; mt++) {
      f16x8 A = *reinterpret_cast<const f16x8*>(wn2t + (mt * 16 + l15) * 128 + k);
#pragma unroll
      for (int nt = 0; nt < 4; nt++)
        acc[mt][nt] = mfma16(A, B[nt], acc[mt][nt]);
    }
  }
#pragma unroll
  for (int mt = 0; mt < 8; mt++) {
    f32x4 bias = *reinterpret_cast<const f32x4*>(bn2 + mt * 16 + quad * 4);
#pragma unroll
    for (int nt = 0; nt < 4; nt++) {
      int n = nbase + nt * 16 + l15;
      if (n < NV) {
        f32x4 v;
#pragma unroll
        for (int r = 0; r < 4; r++) v[r] = acc[mt][nt][r] + bias[r];
        *reinterpret_cast<f32x4*>(out + (long long)n * 128 + mt * 16 + quad * 4) = v;
      }
    }
  }
}

static inline size_t align16(size_t x) { return (x + 15) & ~(size_t)15; }

extern "C" void kernel_launch(void* const* d_in, const int* in_sizes, int n_in,
                              void* d_out, int out_size, void* d_ws, size_t ws_size,
                              hipStream_t stream)
{
  const float* h   = (const float*)d_in[0];
  const int*   ei  = (const int*)d_in[1];
  const float* W1  = (const float*)d_in[2];
  const float* b1  = (const float*)d_in[3];
  const float* W2  = (const float*)d_in[4];
  const float* b2  = (const float*)d_in[5];
  const float* W3  = (const float*)d_in[6];
  const float* b3  = (const float*)d_in[7];
  const float* Wn1 = (const float*)d_in[8];
  const float* bn1 = (const float*)d_in[9];
  const float* Wn2 = (const float*)d_in[10];
  const float* bn2 = (const float*)d_in[11];
  float* out = (float*)d_out;

  char* p = (char*)d_ws;
  _Float16* hf   = (_Float16*)p; p += align16((size_t)NV * 128 * 2);
  _Float16* H1s  = (_Float16*)p; p += align16((size_t)NV * 128 * 2);
  _Float16* H1d  = (_Float16*)p; p += align16((size_t)NV * 128 * 2);
  _Float16* w1st = (_Float16*)p; p += align16(128 * 128 * 2);
  _Float16* w1dt = (_Float16*)p; p += align16(128 * 128 * 2);
  _Float16* w2t  = (_Float16*)p; p += align16(128 * 128 * 2);
  _Float16* wn1c = (_Float16*)p; p += align16(128 * 256 * 2);
  _Float16* wn2t = (_Float16*)p; p += align16(128 * 128 * 2);
  float*  b3n  = (float*)p;  p += align16(128 * 4);
  int* counts  = (int*)p; p += align16((size_t)NV * 4);
  int* offsets = (int*)p; p += align16((size_t)(NV + 1) * 4);
  int* cursor  = (int*)p; p += align16((size_t)NV * 4);
  int* bsum    = (int*)p; p += align16((size_t)(NB1 + 1) * 4);
  int* boff    = (int*)p; p += align16((size_t)(NB1 + 1) * 4);
  int2* pairs  = (int2*)p; p += align16((size_t)NE * 8);
  float* agg2  = (float*)p; p += align16((size_t)NV * 128 * 4);

  hipMemsetAsync(counts, 0, (size_t)NV * 4, stream);
  hipMemsetAsync(agg2, 0, (size_t)NV * 128 * 4, stream);
  {
    int total = CVT_N + TR_N + W3N_N + B3N_N + NE;
    prep_kernel<<<(total + 255) / 256, 256, 0, stream>>>(
        h, hf, W1, W2, W3, Wn1, Wn2, b3,
        w1st, w1dt, w2t, wn1c, wn2t, b3n, ei, counts);
  }
  bsum_kernel<<<NB1, 1024, 0, stream>>>(counts, bsum);
  bscan_kernel<<<1, 64, 0, stream>>>(bsum, boff);
  offs_kernel<<<NB1, 1024, 0, stream>>>(counts, boff, offsets, cursor);
  permute_kernel<<<(NE + 255) / 256, 256, 0, stream>>>(ei, cursor, pairs);
  h1_kernel<<<dim3((NV + 255) / 256, 2), 256, 0, stream>>>(hf, b1, w1st, w1dt, H1s, H1d);
  edge_kernel<<<NE / 128, 128, 0, stream>>>(H1s, H1d, pairs, w2t, b2, agg2);
  node_kernel<<<(NV + 255) / 256, 256, 0, stream>>>(hf, agg2, offsets, wn1c, bn1, b3n,
                                                    wn2t, bn2, out);
}